// Round 8
// baseline (179.062 us; speedup 1.0000x reference)
//
#include <hip/hip_runtime.h>
#include <math.h>

#define Bb 2
#define Ll 2048
#define Dm 1024
#define Ns 16
#define Rr 64
#define Ee 96          // DT_RANK + 2*D_STATE
#define XPS 8          // K-splits for xproj GEMM (K-slice = 128)
#define BLK (Bb*Ll)    // 4096 rows
#define NTHR 256
#define CH 64          // chunks
#define CL 32          // chunk length

// ========== Kernel 1: xproj split-K GEMM. BM=64, k-major LDS, b128/b64 fragment reads ==========
// grid = 64 mtiles x 8 ksplits = 512 blocks (2/CU). K-slice 128 staged in 4 sub-chunks of 32.
__global__ void __launch_bounds__(NTHR)
k_xproj(const float* __restrict__ x, const float* __restrict__ xw,
        float* __restrict__ xp_part) {
    __shared__ float xsT[32 * 68];    // [k][row]
    __shared__ float wT [32 * 100];   // [k][e]
    int bx = blockIdx.x;
    int ks = bx & 7, mt = bx >> 3;
    int i0 = mt * 64;
    int tid = threadIdx.x;
    int tx = tid & 15, ty = tid >> 4;    // thread tile: 4 rows x 6 cols

    float acc[4][6];
#pragma unroll
    for (int ii = 0; ii < 4; ++ii)
#pragma unroll
        for (int jj = 0; jj < 6; ++jj) acc[ii][jj] = 0.f;

    for (int kc = 0; kc < 4; ++kc) {
        int k0 = ks * 128 + kc * 32;
        for (int t = tid; t < 512; t += NTHR) {          // x: 64 rows x 32 k
            int r = t >> 3, c = (t & 7) * 4;
            float4 v = *(const float4*)(x + (size_t)(i0 + r) * Dm + k0 + c);
            xsT[(c+0)*68 + r] = v.x; xsT[(c+1)*68 + r] = v.y;
            xsT[(c+2)*68 + r] = v.z; xsT[(c+3)*68 + r] = v.w;
        }
        for (int t = tid; t < 768; t += NTHR) {          // w: 96 rows x 32 k
            int r = t >> 3, c = (t & 7) * 4;
            float4 v = *(const float4*)(xw + (size_t)r * Dm + k0 + c);
            wT[(c+0)*100 + r] = v.x; wT[(c+1)*100 + r] = v.y;
            wT[(c+2)*100 + r] = v.z; wT[(c+3)*100 + r] = v.w;
        }
        __syncthreads();
#pragma unroll 8
        for (int k = 0; k < 32; ++k) {
            float xv[4], wv[6];
            *(float4*)xv     = *(const float4*)(xsT + k*68 + ty*4);
            *(float2*)(wv)   = *(const float2*)(wT + k*100 + tx*6);
            *(float2*)(wv+2) = *(const float2*)(wT + k*100 + tx*6 + 2);
            *(float2*)(wv+4) = *(const float2*)(wT + k*100 + tx*6 + 4);
#pragma unroll
            for (int ii = 0; ii < 4; ++ii)
#pragma unroll
                for (int jj = 0; jj < 6; ++jj)
                    acc[ii][jj] = fmaf(xv[ii], wv[jj], acc[ii][jj]);
        }
        __syncthreads();
    }
#pragma unroll
    for (int ii = 0; ii < 4; ++ii)
#pragma unroll
        for (int jj = 0; jj < 6; ++jj)
            xp_part[((size_t)ks * BLK + (i0 + ty*4 + ii)) * Ee + tx*6 + jj] = acc[ii][jj];
}

// ========== Kernel 2: fused [split-K reduce + delta GEMM + softplus]; nt==0 also emits xpBC ==========
// BM=64, BN=64 -> 64 mt x 16 nt = 1024 blocks (4/CU). k-major LDS, b128 fragment reads.
__global__ void __launch_bounds__(NTHR)
k_delta(const float* __restrict__ xp_part, const float* __restrict__ dtw,
        const float* __restrict__ dtb, float* __restrict__ delta,
        float* __restrict__ xpBC) {
    __shared__ float xsT[64 * 68];    // [k][row] (reduced d_rank slice)
    __shared__ float wT [64 * 68];    // [k][d-local]
    int bx = blockIdx.x;
    int nt = bx & 15, mt = bx >> 4;   // consecutive bx share mt -> L2 reuse of xp_part
    int i0 = mt * 64, j0 = nt * 64;
    int tid = threadIdx.x, tx = tid & 15, ty = tid >> 4;

    for (int t = tid; t < 1024; t += NTHR) {
        int r = t >> 4, c = (t & 15) * 4;
        float4 s = make_float4(0.f, 0.f, 0.f, 0.f);
#pragma unroll
        for (int i = 0; i < XPS; ++i) {
            float4 v = *(const float4*)(xp_part + ((size_t)i * BLK + i0 + r) * Ee + c);
            s.x += v.x; s.y += v.y; s.z += v.z; s.w += v.w;
        }
        xsT[(c+0)*68 + r] = s.x; xsT[(c+1)*68 + r] = s.y;
        xsT[(c+2)*68 + r] = s.z; xsT[(c+3)*68 + r] = s.w;
        float4 w = *(const float4*)(dtw + (size_t)(j0 + r) * Rr + c);
        wT[(c+0)*68 + r] = w.x; wT[(c+1)*68 + r] = w.y;
        wT[(c+2)*68 + r] = w.z; wT[(c+3)*68 + r] = w.w;
    }
    if (nt == 0) {   // reduce B/C cols 64..95 -> compact xpBC for this row-block
        for (int t = tid; t < 512; t += NTHR) {
            int r = t >> 3, cc = (t & 7) * 4;
            float4 s = make_float4(0.f, 0.f, 0.f, 0.f);
#pragma unroll
            for (int i = 0; i < XPS; ++i) {
                float4 v = *(const float4*)(xp_part + ((size_t)i * BLK + i0 + r) * Ee + Rr + cc);
                s.x += v.x; s.y += v.y; s.z += v.z; s.w += v.w;
            }
            *(float4*)(xpBC + (size_t)(i0 + r) * 32 + cc) = s;
        }
    }
    __syncthreads();

    float acc[4][4];
#pragma unroll
    for (int ii = 0; ii < 4; ++ii)
#pragma unroll
        for (int jj = 0; jj < 4; ++jj) acc[ii][jj] = 0.f;
#pragma unroll 8
    for (int k = 0; k < 64; ++k) {
        float xv[4], wv[4];
        *(float4*)xv = *(const float4*)(xsT + k*68 + ty*4);
        *(float4*)wv = *(const float4*)(wT  + k*68 + tx*4);
#pragma unroll
        for (int ii = 0; ii < 4; ++ii)
#pragma unroll
            for (int jj = 0; jj < 4; ++jj)
                acc[ii][jj] = fmaf(xv[ii], wv[jj], acc[ii][jj]);
    }
    int d0 = j0 + tx * 4;
    float4 bias = *(const float4*)(dtb + d0);
#pragma unroll
    for (int ii = 0; ii < 4; ++ii) {
        int bl = i0 + ty*4 + ii;
        float z0 = acc[ii][0] + bias.x, z1 = acc[ii][1] + bias.y;
        float z2 = acc[ii][2] + bias.z, z3 = acc[ii][3] + bias.w;
        float4 o;
        o.x = fmaxf(z0, 0.f) + log1pf(__expf(-fabsf(z0)));
        o.y = fmaxf(z1, 0.f) + log1pf(__expf(-fabsf(z1)));
        o.z = fmaxf(z2, 0.f) + log1pf(__expf(-fabsf(z2)));
        o.w = fmaxf(z3, 0.f) + log1pf(__expf(-fabsf(z3)));
        *(float4*)(delta + (size_t)bl * Dm + d0) = o;
    }
}

// ---- helper: load A row into regs ----
__device__ inline void load_a(const float* __restrict__ A_log, int d, float* a) {
    const float4* Ap = (const float4*)(A_log + (size_t)d * Ns);
    float4 a0 = Ap[0], a1 = Ap[1], a2 = Ap[2], a3 = Ap[3];
    float tmp[Ns] = {a0.x,a0.y,a0.z,a0.w, a1.x,a1.y,a1.z,a1.w,
                     a2.x,a2.y,a2.z,a2.w, a3.x,a3.y,a3.z,a3.w};
#pragma unroll
    for (int n = 0; n < Ns; ++n) a[n] = -__expf(tmp[n]);
}

// ========== Kernel 3: per-chunk local scan (h0=0) -> Ec, Sc ==========
// grid = Bb*CH*4 = 512 blocks. BC chunk staged in LDS (4 KB).
__global__ void __launch_bounds__(NTHR)
k_scan_part(const float* __restrict__ delta, const float* __restrict__ x,
            const float* __restrict__ xpBC, const float* __restrict__ A_log,
            float* __restrict__ Ec, float* __restrict__ Sc) {
    __shared__ float BCs[CL * 32];
    int bx = blockIdx.x;
    int dblk = bx & 3, chunk = (bx >> 2) & (CH - 1), b = bx >> 8;
    int tid = threadIdx.x;
    int d = dblk * 256 + tid;
    int row0 = b * Ll + chunk * CL;

    {   // CL*8 = 256 tasks: one float4 per thread
        int r = tid >> 3, c = (tid & 7) * 4;
        *(float4*)(BCs + r*32 + c) = *(const float4*)(xpBC + (size_t)(row0 + r) * 32 + c);
    }
    float a[Ns], h[Ns];
    load_a(A_log, d, a);
#pragma unroll
    for (int n = 0; n < Ns; ++n) h[n] = 0.f;
    float sd = 0.f;
    __syncthreads();

#pragma unroll 4
    for (int t = 0; t < CL; ++t) {
        size_t row = (size_t)(row0 + t);
        float dl = delta[row * Dm + d];
        float xv = x[row * Dm + d];
        const float* bp = BCs + t*32;
        float4 B0 = *(const float4*)(bp + 0),  B1 = *(const float4*)(bp + 4);
        float4 B2 = *(const float4*)(bp + 8),  B3 = *(const float4*)(bp + 12);
        float Bv[Ns] = {B0.x,B0.y,B0.z,B0.w, B1.x,B1.y,B1.z,B1.w,
                        B2.x,B2.y,B2.z,B2.w, B3.x,B3.y,B3.z,B3.w};
        float dx = dl * xv;
        sd += dl;
#pragma unroll
        for (int n = 0; n < Ns; ++n)
            h[n] = fmaf(__expf(dl * a[n]), h[n], dx * Bv[n]);
    }
    size_t base = ((size_t)b * CH + chunk) * Dm + d;
    float4* Ep = (float4*)(Ec + base * Ns);
    Ep[0] = make_float4(h[0],  h[1],  h[2],  h[3]);
    Ep[1] = make_float4(h[4],  h[5],  h[6],  h[7]);
    Ep[2] = make_float4(h[8],  h[9],  h[10], h[11]);
    Ep[3] = make_float4(h[12], h[13], h[14], h[15]);
    Sc[base] = sd;
}

// ========== Kernel 4: sequential combine over chunks -> Hin ==========
__global__ void __launch_bounds__(NTHR)
k_combine(const float* __restrict__ Ec, const float* __restrict__ Sc,
          const float* __restrict__ A_log, float* __restrict__ Hin) {
    int gid = blockIdx.x * NTHR + threadIdx.x;   // < Bb*Dm*Ns = 32768
    int n = gid & (Ns - 1);
    int d = (gid >> 4) & (Dm - 1);
    int b = gid >> 14;
    float a = -__expf(A_log[d * Ns + n]);
    float h = 0.f;
#pragma unroll 4
    for (int c = 0; c < CH; ++c) {
        size_t base = ((size_t)b * CH + c) * Dm + d;
        Hin[base * Ns + n] = h;
        float P = __expf(a * Sc[base]);
        h = fmaf(P, h, Ec[base * Ns + n]);
    }
}

// ========== Kernel 5: full scan from true h_in, emit y ==========
__global__ void __launch_bounds__(NTHR)
k_scan_full(const float* __restrict__ delta, const float* __restrict__ x,
            const float* __restrict__ xpBC, const float* __restrict__ A_log,
            const float* __restrict__ Dp, const float* __restrict__ Hin,
            float* __restrict__ out) {
    __shared__ float BCs[CL * 32];
    int bx = blockIdx.x;
    int dblk = bx & 3, chunk = (bx >> 2) & (CH - 1), b = bx >> 8;
    int tid = threadIdx.x;
    int d = dblk * 256 + tid;
    int row0 = b * Ll + chunk * CL;

    {
        int r = tid >> 3, c = (tid & 7) * 4;
        *(float4*)(BCs + r*32 + c) = *(const float4*)(xpBC + (size_t)(row0 + r) * 32 + c);
    }
    float a[Ns], h[Ns];
    load_a(A_log, d, a);
    size_t base = ((size_t)b * CH + chunk) * Dm + d;
    {
        const float4* Hp = (const float4*)(Hin + base * Ns);
        float4 h0 = Hp[0], h1 = Hp[1], h2 = Hp[2], h3 = Hp[3];
        h[0]=h0.x; h[1]=h0.y; h[2]=h0.z; h[3]=h0.w;
        h[4]=h1.x; h[5]=h1.y; h[6]=h1.z; h[7]=h1.w;
        h[8]=h2.x; h[9]=h2.y; h[10]=h2.z; h[11]=h2.w;
        h[12]=h3.x; h[13]=h3.y; h[14]=h3.z; h[15]=h3.w;
    }
    float Dval = Dp[d];
    __syncthreads();

#pragma unroll 4
    for (int t = 0; t < CL; ++t) {
        size_t row = (size_t)(row0 + t);
        float dl = delta[row * Dm + d];
        float xv = x[row * Dm + d];
        const float* bp = BCs + t*32;
        float4 B0 = *(const float4*)(bp + 0),  B1 = *(const float4*)(bp + 4);
        float4 B2 = *(const float4*)(bp + 8),  B3 = *(const float4*)(bp + 12);
        float4 C0 = *(const float4*)(bp + 16), C1 = *(const float4*)(bp + 20);
        float4 C2 = *(const float4*)(bp + 24), C3 = *(const float4*)(bp + 28);
        float Bv[Ns] = {B0.x,B0.y,B0.z,B0.w, B1.x,B1.y,B1.z,B1.w,
                        B2.x,B2.y,B2.z,B2.w, B3.x,B3.y,B3.z,B3.w};
        float Cv[Ns] = {C0.x,C0.y,C0.z,C0.w, C1.x,C1.y,C1.z,C1.w,
                        C2.x,C2.y,C2.z,C2.w, C3.x,C3.y,C3.z,C3.w};
        float dx = dl * xv;
        float y = 0.f;
#pragma unroll
        for (int n = 0; n < Ns; ++n) {
            h[n] = fmaf(__expf(dl * a[n]), h[n], dx * Bv[n]);
            y = fmaf(h[n], Cv[n], y);
        }
        out[row * Dm + d] = fmaf(xv, Dval, y);
    }
}

extern "C" void kernel_launch(void* const* d_in, const int* in_sizes, int n_in,
                              void* d_out, int out_size, void* d_ws, size_t ws_size,
                              hipStream_t stream) {
    const float* x     = (const float*)d_in[0];
    const float* A_log = (const float*)d_in[1];
    const float* Dp    = (const float*)d_in[2];
    const float* xw    = (const float*)d_in[3];
    const float* dtw   = (const float*)d_in[4];
    const float* dtb   = (const float*)d_in[5];
    float* out = (float*)d_out;
    float* ws  = (float*)d_ws;

    // workspace layout (floats), no aliasing (47 MB total, ws is ~268 MB):
    float* xpBC    = ws;                          //   131,072
    float* delta   = xpBC    + 131072;            // 4,194,304
    float* xp_part = delta   + 4194304;           // 3,145,728 (8 * 393216)
    float* Ec      = xp_part + 3145728;           // 2,097,152 (2*64*1024*16)
    float* Sc      = Ec      + 2097152;           //   131,072
    float* Hin     = Sc      + 131072;            // 2,097,152

    k_xproj    <<<dim3(512),  dim3(NTHR), 0, stream>>>(x, xw, xp_part);
    k_delta    <<<dim3(1024), dim3(NTHR), 0, stream>>>(xp_part, dtw, dtb, delta, xpBC);
    k_scan_part<<<dim3(512),  dim3(NTHR), 0, stream>>>(delta, x, xpBC, A_log, Ec, Sc);
    k_combine  <<<dim3(128),  dim3(NTHR), 0, stream>>>(Ec, Sc, A_log, Hin);
    k_scan_full<<<dim3(512),  dim3(NTHR), 0, stream>>>(delta, x, xpBC, A_log, Dp, Hin, out);
}